// Round 1
// baseline (1948.206 us; speedup 1.0000x reference)
//
#include <hip/hip_runtime.h>

#define BB 256
#define SS 64
#define HH 512
#define VV 32000

typedef unsigned short u16;
typedef __attribute__((ext_vector_type(8))) short bf16x8;   // 8 bf16 = 4 VGPRs
typedef __attribute__((ext_vector_type(4))) float f32x4;    // MFMA 16x16 C/D

__device__ __forceinline__ float sigm(float x) { return 1.0f / (1.0f + __expf(-x)); }
__device__ __forceinline__ float tanh_fast(float x) { return 1.0f - 2.0f / (__expf(2.0f * x) + 1.0f); }
__device__ __forceinline__ u16 f2bf(float f) {              // RNE fp32 -> bf16
    unsigned u = __float_as_uint(f);
    return (u16)((u + 0x7fffu + ((u >> 16) & 1u)) >> 16);
}
__device__ __forceinline__ bf16x8 ld_cvt8(const float* s) { // 8 fp32 -> bf16x8
    float4 v0 = *(const float4*)s, v1 = *(const float4*)(s + 4);
    bf16x8 b;
    b[0] = (short)f2bf(v0.x); b[1] = (short)f2bf(v0.y);
    b[2] = (short)f2bf(v0.z); b[3] = (short)f2bf(v0.w);
    b[4] = (short)f2bf(v1.x); b[5] = (short)f2bf(v1.y);
    b[6] = (short)f2bf(v1.z); b[7] = (short)f2bf(v1.w);
    return b;
}

#define MFMA(a, b, c) __builtin_amdgcn_mfma_f32_16x16x32_bf16(a, b, c, 0, 0, 0)

// ---------------------------------------------------------------------------
// pack_k: one-time swizzle into MFMA fragment layouts (wave-task based).
//  Xfrag  [s][mt][kc][lane][8]            : embedded seq, A-frag order, 16 MB
//  Wfsw/Wbsw [ut][kc 0..31][g][lane][8]   : fused [Wih|Whh] f/b, 4 MB each
//  Wcsw   [ut][kc 0..63][g][lane][8]      : fused [Wih_c|Whh_c], 16 MB
// B-frag elem (lane=(l15,quad), j) = W[row = g*NU + ut*16 + l15][kc*32+quad*8+j]
// ---------------------------------------------------------------------------
__global__ __launch_bounds__(256)
void pack_k(const int* __restrict__ x, const float* __restrict__ W_emb,
            const float* __restrict__ Wih_f, const float* __restrict__ Whh_f,
            const float* __restrict__ Wih_b, const float* __restrict__ Whh_b,
            const float* __restrict__ Wih_c, const float* __restrict__ Whh_c,
            u16* __restrict__ Xfrag, u16* __restrict__ Wfsw,
            u16* __restrict__ Wbsw, u16* __restrict__ Wcsw)
{
    const int lane = threadIdx.x & 63;
    const int l15 = lane & 15, quad = lane >> 4;
    const int gw0 = blockIdx.x * 4 + (threadIdx.x >> 6);
    const int nw = gridDim.x * 4;
    for (int task = gw0; task < 40960; task += nw) {
        const float* src; u16* dst; float scale = 1.f;
        if (task < 16384) {                         // Xfrag: (s, mt, kc)
            int s = task >> 8, rem = task & 255, mt = rem >> 4, kc = rem & 15;
            int b = mt * 16 + l15;
            int tok = x[s * 256 + b];               // raw reshape: row = s*256+b
            scale = (tok == 0) ? 0.f : 1.f;         // padding_idx=0
            src = W_emb + (size_t)tok * 512 + kc * 32 + quad * 8;
            dst = Xfrag + ((size_t)(s * 16 + mt) * 16 + kc) * 512 + (size_t)lane * 8;
        } else if (task < 24576) {                  // Wf / Wb: (which, ut, kc, g)
            int e = task - 16384;
            int which = e >> 12; e &= 4095;
            int ut = e >> 7, rem = e & 127, kc = rem >> 2, g = rem & 3;
            int row = g * 512 + ut * 16 + l15;
            int k0 = kc * 32 + quad * 8;
            const float* Wih = which ? Wih_b : Wih_f;
            const float* Whh = which ? Whh_b : Whh_f;
            src = (k0 < 512) ? (Wih + (size_t)row * 512 + k0)
                             : (Whh + (size_t)row * 512 + (k0 - 512));
            u16* W = which ? Wbsw : Wfsw;
            dst = W + ((size_t)(ut * 32 + kc) * 4 + g) * 512 + (size_t)lane * 8;
        } else {                                    // Wc: (ut, kc, g)
            int e = task - 24576;
            int ut = e >> 8, rem = e & 255, kc = rem >> 2, g = rem & 3;
            int row = g * 1024 + ut * 16 + l15;
            int k0 = kc * 32 + quad * 8;
            src = (k0 < 1024) ? (Wih_c + (size_t)row * 1024 + k0)
                              : (Whh_c + (size_t)row * 1024 + (k0 - 1024));
            dst = Wcsw + ((size_t)(ut * 64 + kc) * 4 + g) * 512 + (size_t)lane * 8;
        }
        float4 v0 = *(const float4*)src;
        float4 v1 = *(const float4*)(src + 4);
        bf16x8 o;
        o[0] = (short)f2bf(v0.x * scale); o[1] = (short)f2bf(v0.y * scale);
        o[2] = (short)f2bf(v0.z * scale); o[3] = (short)f2bf(v0.w * scale);
        o[4] = (short)f2bf(v1.x * scale); o[5] = (short)f2bf(v1.y * scale);
        o[6] = (short)f2bf(v1.z * scale); o[7] = (short)f2bf(v1.w * scale);
        *(bf16x8*)dst = o;
    }
}

// ---------------------------------------------------------------------------
// init_k: bias sums + initial states. h0 -> bf16 A-FRAGMENT layout, c -> fp32.
// frag addr for h[b][k], NKC frags/mt: ((b>>4)*NKC + (k>>5))*512 +
//   ((b&15) + ((k>>3)&3)*16)*8 + (k&7)
// ---------------------------------------------------------------------------
__global__ __launch_bounds__(256)
void init_k(const float* __restrict__ bih_f, const float* __restrict__ bhh_f,
            const float* __restrict__ bih_b, const float* __restrict__ bhh_b,
            const float* __restrict__ bih_c, const float* __restrict__ bhh_c,
            const float* __restrict__ h0f, const float* __restrict__ c0f,
            const float* __restrict__ h0b, const float* __restrict__ c0b,
            const float* __restrict__ h0c, const float* __restrict__ c0c,
            float* __restrict__ bsf, float* __restrict__ bsb, float* __restrict__ bsc,
            u16* __restrict__ hf0, u16* __restrict__ hb0, u16* __restrict__ hc0,
            float* __restrict__ cf, float* __restrict__ cb, float* __restrict__ cc)
{
    const int gid = blockIdx.x * 256 + threadIdx.x;
    if (gid < 2048)       bsf[gid] = bih_f[gid] + bhh_f[gid];
    else if (gid < 4096)  { int e = gid - 2048; bsb[e] = bih_b[e] + bhh_b[e]; }
    else if (gid < 8192)  { int e = gid - 4096; bsc[e] = bih_c[e] + bhh_c[e]; }
    const int stride = gridDim.x * 256;
    for (int i = gid; i < 131072; i += stride) {
        int b = i >> 9, k = i & 511;
        int dst = ((b >> 4) * 16 + (k >> 5)) * 512 + (((b & 15) + (((k >> 3) & 3) << 4)) << 3) + (k & 7);
        hf0[dst] = f2bf(h0f[i]);
        hb0[dst] = f2bf(h0b[i]);
        cf[i] = c0f[i];
        cb[i] = c0b[i];
    }
    for (int i = gid; i < 262144; i += stride) {
        int b = i >> 10, k = i & 1023;
        int dst = ((b >> 4) * 32 + (k >> 5)) * 512 + (((b & 15) + (((k >> 3) & 3) << 4)) << 3) + (k & 7);
        hc0[dst] = f2bf(h0c[i]);
        cc[i] = c0c[i];
    }
}

// One double-buffered 2-kc GEMM period: stage next B (gate w) to LDS,
// 16 MFMA (2 mt x 4 g x 2 kc), single barrier.
#define PERIODS(A0, A1, PS, PE, NPT)                                        \
  for (int p = (PS); p < (PE); ++p) {                                       \
    const int cur = p & 1, nxt = cur ^ 1;                                   \
    const int kl = p - (PS);                                                \
    bf16x8 sa, sb;                                                          \
    const bool pre = (p + 1 < (NPT));                                       \
    if (pre) {                                                              \
      sa = *(const bf16x8*)(wstage + (size_t)(2 * p + 2) * 2048);           \
      sb = *(const bf16x8*)(wstage + (size_t)(2 * p + 3) * 2048);           \
    }                                                                       \
    bf16x8 a00 = *(const bf16x8*)((A0) + (size_t)(2 * kl) * 512);           \
    bf16x8 a01 = *(const bf16x8*)((A1) + (size_t)(2 * kl) * 512);           \
    bf16x8 a10 = *(const bf16x8*)((A0) + (size_t)(2 * kl + 1) * 512);       \
    bf16x8 a11 = *(const bf16x8*)((A1) + (size_t)(2 * kl + 1) * 512);       \
    _Pragma("unroll")                                                       \
    for (int g = 0; g < 4; ++g) {                                           \
      bf16x8 b0 = *(const bf16x8*)&Bsh[cur][0][g][(size_t)lane * 8];        \
      bf16x8 b1 = *(const bf16x8*)&Bsh[cur][1][g][(size_t)lane * 8];        \
      acc[0][g] = MFMA(a00, b0, acc[0][g]);                                 \
      acc[1][g] = MFMA(a01, b0, acc[1][g]);                                 \
      acc[0][g] = MFMA(a10, b1, acc[0][g]);                                 \
      acc[1][g] = MFMA(a11, b1, acc[1][g]);                                 \
    }                                                                       \
    if (pre) {                                                              \
      *(bf16x8*)&Bsh[nxt][0][w][(size_t)lane * 8] = sa;                     \
      *(bf16x8*)&Bsh[nxt][1][w][(size_t)lane * 8] = sb;                     \
    }                                                                       \
    __syncthreads();                                                        \
  }

// ---------------------------------------------------------------------------
// step_k v4: 256 blocks, XCD-swizzled (blockIdx%8 = XCD), 4 waves = 4 gates.
//  slot<16 : fb cell step t   (cell = xcd>>2, ut = (xcd&3)*8+slot>>1, mh)
//  slot>=16: combiner step t-1 (ut = xcd*8 + (slot-16)>>1, mh)
// Per-XCD weight working set: 1 MB (fb) + 2 MB (comb) -> L2-resident.
// Wave: 2 m-tiles x 4 gates, B through LDS (staged once per block).
// ---------------------------------------------------------------------------
__global__ __launch_bounds__(256)
void step_k(const u16* __restrict__ Xfrag,
            const u16* __restrict__ Wfsw, const u16* __restrict__ Wbsw,
            const u16* __restrict__ Wcsw,
            const float* __restrict__ bsf, const float* __restrict__ bsb,
            const float* __restrict__ bsc,
            const u16* __restrict__ hf_r, u16* __restrict__ hf_w, float* __restrict__ cf,
            const u16* __restrict__ hb_r, u16* __restrict__ hb_w, float* __restrict__ cb,
            const u16* __restrict__ hc_r, u16* __restrict__ hc_w, float* __restrict__ cc,
            int t)
{
    __shared__ __align__(16) u16 Bsh[2][2][4][512];   // 16 KB
    const int tid = threadIdx.x;
    const int w = tid >> 6, lane = tid & 63;
    const int l15 = lane & 15, quad = lane >> 4;
    const int xcd = blockIdx.x & 7, slot = blockIdx.x >> 3;
    const f32x4 z = {0.f, 0.f, 0.f, 0.f};

    if (slot < 16) {
        // ---------------- fb cells, step t ----------------
        if (t >= SS) return;
        const int mh = slot & 1, cell = xcd >> 2;
        const int ut = (xcd & 3) * 8 + (slot >> 1);
        const int mt0 = mh * 8 + w * 2;
        const u16* Wsw = cell ? Wbsw : Wfsw;
        const float* bs = cell ? bsb : bsf;
        const u16* h_r = cell ? hb_r : hf_r;
        u16* h_w = cell ? hb_w : hf_w;
        float* c = cell ? cb : cf;
        const int s2 = cell ? (SS - 1 - t) : t;

        const u16* wstage = Wsw + (size_t)ut * 65536 + (size_t)w * 512 + (size_t)lane * 8;
        const u16* xb0 = Xfrag + ((size_t)(s2 * 16 + mt0) * 16) * 512 + (size_t)lane * 8;
        const u16* xb1 = xb0 + 16 * 512;
        const u16* hp0 = h_r + ((size_t)(mt0 * 16)) * 512 + (size_t)lane * 8;
        const u16* hp1 = hp0 + 16 * 512;

        f32x4 acc[2][4];
#pragma unroll
        for (int mi = 0; mi < 2; ++mi)
#pragma unroll
            for (int g = 0; g < 4; ++g) acc[mi][g] = z;

        {   // prologue: stage kc 0,1
            bf16x8 s0 = *(const bf16x8*)(wstage);
            bf16x8 s1 = *(const bf16x8*)(wstage + 2048);
            *(bf16x8*)&Bsh[0][0][w][(size_t)lane * 8] = s0;
            *(bf16x8*)&Bsh[0][1][w][(size_t)lane * 8] = s1;
            __syncthreads();
        }
        PERIODS(xb0, xb1, 0, 8, 16)     // K 0..511: embedded input
        PERIODS(hp0, hp1, 8, 16, 16)    // K 512..1023: recurrent h

        const int u = ut * 16 + l15;
        const float bi_ = bs[u], bf_ = bs[512 + u], bg_ = bs[1024 + u], bo_ = bs[1536 + u];
        const int fragk = ut >> 1;
        const int lanehi = ((ut & 1) * 2 + (l15 >> 3)) << 4;
        const int j = l15 & 7;
#pragma unroll
        for (int mi = 0; mi < 2; ++mi) {
            const int mt = mt0 + mi;
#pragma unroll
            for (int r = 0; r < 4; ++r) {
                const int b = mt * 16 + quad * 4 + r;
                const size_t ci = (size_t)b * 512 + u;
                float i_ = sigm(acc[mi][0][r] + bi_);
                float f_ = sigm(acc[mi][1][r] + bf_);
                float g_ = tanh_fast(acc[mi][2][r] + bg_);
                float o_ = sigm(acc[mi][3][r] + bo_);
                float c2 = f_ * c[ci] + i_ * g_;
                c[ci] = c2;
                h_w[(size_t)(mt * 16 + fragk) * 512 + (size_t)((quad * 4 + r) + lanehi) * 8 + j]
                    = f2bf(o_ * tanh_fast(c2));
            }
        }
    } else {
        // ---------------- combiner, step t-1 ----------------
        if (t == 0) return;
        const int cs = slot - 16;
        const int mh = cs & 1;
        const int ut = xcd * 8 + (cs >> 1);
        const int mt0 = mh * 8 + w * 2;

        const u16* wstage = Wcsw + (size_t)ut * 131072 + (size_t)w * 512 + (size_t)lane * 8;
        const u16* hfp0 = hf_r + ((size_t)(mt0 * 16)) * 512 + (size_t)lane * 8;
        const u16* hfp1 = hfp0 + 16 * 512;
        const u16* hbp0 = hb_r + ((size_t)(mt0 * 16)) * 512 + (size_t)lane * 8;
        const u16* hbp1 = hbp0 + 16 * 512;
        const u16* hcp0 = hc_r + ((size_t)(mt0 * 32)) * 512 + (size_t)lane * 8;
        const u16* hcp1 = hcp0 + 32 * 512;

        f32x4 acc[2][4];
#pragma unroll
        for (int mi = 0; mi < 2; ++mi)
#pragma unroll
            for (int g = 0; g < 4; ++g) acc[mi][g] = z;

        {
            bf16x8 s0 = *(const bf16x8*)(wstage);
            bf16x8 s1 = *(const bf16x8*)(wstage + 2048);
            *(bf16x8*)&Bsh[0][0][w][(size_t)lane * 8] = s0;
            *(bf16x8*)&Bsh[0][1][w][(size_t)lane * 8] = s1;
            __syncthreads();
        }
        PERIODS(hfp0, hfp1, 0, 8, 32)    // K 0..511: hf(t-1)
        PERIODS(hbp0, hbp1, 8, 16, 32)   // K 512..1023: hb(t-1)
        PERIODS(hcp0, hcp1, 16, 32, 32)  // K 1024..2047: hc(t-2)

        const int u = ut * 16 + l15;
        const float bi_ = bsc[u], bf_ = bsc[1024 + u], bg_ = bsc[2048 + u], bo_ = bsc[3072 + u];
        const int fragk = ut >> 1;
        const int lanehi = ((ut & 1) * 2 + (l15 >> 3)) << 4;
        const int j = l15 & 7;
#pragma unroll
        for (int mi = 0; mi < 2; ++mi) {
            const int mt = mt0 + mi;
#pragma unroll
            for (int r = 0; r < 4; ++r) {
                const int b = mt * 16 + quad * 4 + r;
                const size_t ci = (size_t)b * 1024 + u;
                float i_ = sigm(acc[mi][0][r] + bi_);
                float f_ = sigm(acc[mi][1][r] + bf_);
                float g_ = tanh_fast(acc[mi][2][r] + bg_);
                float o_ = sigm(acc[mi][3][r] + bo_);
                float c2 = f_ * cc[ci] + i_ * g_;
                cc[ci] = c2;
                hc_w[(size_t)(mt * 32 + fragk) * 512 + (size_t)((quad * 4 + r) + lanehi) * 8 + j]
                    = f2bf(o_ * tanh_fast(c2));
            }
        }
    }
}

// ---------------------------------------------------------------------------
// head_v3: out(256,32000) = hc(frag) @ bf16(Wout)^T + bout.
// 500 blocks x 4 waves. Wave w stages n-tile (bid*4+w) of Wout (fp32->bf16,
// once per block) into LDS; computes m-quarter (wid*4..+3 m-tiles) x 4 nt.
// W read once (131 MB, L3-warm); A from L2.
// ---------------------------------------------------------------------------
__global__ __launch_bounds__(256)
void head_v3(const u16* __restrict__ A,        // (256,1024) bf16 frag, NKC=32
             const float* __restrict__ W,      // (32000,1024) fp32
             const float* __restrict__ bias,
             float* __restrict__ out)          // (256,32000) fp32
{
    __shared__ __align__(16) u16 Bsh[2][2][4][512];   // 16 KB
    const int tid = threadIdx.x;
    const int w = tid >> 6, lane = tid & 63;
    const int l15 = lane & 15, quad = lane >> 4;
    const int bid = blockIdx.x;
    const int ntw = bid * 4 + w;                       // staged n-tile

    const float* wsrc = W + (size_t)(ntw * 16 + l15) * 1024 + (size_t)quad * 8;
    const u16* ha[4];
#pragma unroll
    for (int mi = 0; mi < 4; ++mi)
        ha[mi] = A + ((size_t)((w * 4 + mi) * 32)) * 512 + (size_t)lane * 8;

    f32x4 acc[4][4];
#pragma unroll
    for (int mi = 0; mi < 4; ++mi)
#pragma unroll
        for (int nt = 0; nt < 4; ++nt) acc[mi][nt] = {0.f, 0.f, 0.f, 0.f};

    {   // prologue: stage kc 0,1
        bf16x8 s0 = ld_cvt8(wsrc);
        bf16x8 s1 = ld_cvt8(wsrc + 32);
        *(bf16x8*)&Bsh[0][0][w][(size_t)lane * 8] = s0;
        *(bf16x8*)&Bsh[0][1][w][(size_t)lane * 8] = s1;
        __syncthreads();
    }
    for (int p = 0; p < 16; ++p) {
        const int cur = p & 1, nxt = cur ^ 1;
        bf16x8 sa, sb;
        const bool pre = (p + 1 < 16);
        if (pre) {
            sa = ld_cvt8(wsrc + (size_t)(2 * p + 2) * 32);
            sb = ld_cvt8(wsrc + (size_t)(2 * p + 3) * 32);
        }
        bf16x8 a0[4], a1[4];
#pragma unroll
        for (int mi = 0; mi < 4; ++mi) {
            a0[mi] = *(const bf16x8*)(ha[mi] + (size_t)(2 * p) * 512);
            a1[mi] = *(const bf16x8*)(ha[mi] + (size_t)(2 * p + 1) * 512);
        }
#pragma unroll
        for (int nt = 0; nt < 4; ++nt) {
            bf16x8 b0 = *(const bf16x8*)&Bsh[cur][0][nt][(size_t)lane * 8];
            bf16x8 b1 = *(const bf16x8*)&Bsh[cur][1][nt][(size_t)lane * 8];
#pragma unroll
            for (int mi = 0; mi < 4; ++mi) {
                acc[mi][nt] = MFMA(a0[mi], b0, acc[mi][nt]);
                acc[mi][nt] = MFMA(a1[mi], b1, acc[mi][nt]);
            }
        }
        if (pre) {
            *(bf16x8*)&Bsh[nxt][0][w][(size_t)lane * 8] = sa;
            *(bf16x8*)&Bsh[nxt][1][w][(size_t)lane * 8] = sb;
        }
        __syncthreads();
    }

#pragma unroll
    for (int nt = 0; nt < 4; ++nt) {
        const int n = (bid * 4 + nt) * 16 + l15;
        const float bv = bias[n];
#pragma unroll
        for (int mi = 0; mi < 4; ++mi) {
            const int mt = w * 4 + mi;
#pragma unroll
            for (int r = 0; r < 4; ++r)
                out[(size_t)(mt * 16 + quad * 4 + r) * VV + n] = acc[mi][nt][r] + bv;
        }
    }
}

extern "C" void kernel_launch(void* const* d_in, const int* in_sizes, int n_in,
                              void* d_out, int out_size, void* d_ws, size_t ws_size,
                              hipStream_t stream) {
    const int*   x     = (const int*)d_in[0];
    const float* W_emb = (const float*)d_in[1];
    const float* Wih_f = (const float*)d_in[2];
    const float* Whh_f = (const float*)d_in[3];
    const float* bih_f = (const float*)d_in[4];
    const float* bhh_f = (const float*)d_in[5];
    const float* Wih_b = (const float*)d_in[6];
    const float* Whh_b = (const float*)d_in[7];
    const float* bih_b = (const float*)d_in[8];
    const float* bhh_b = (const float*)d_in[9];
    const float* Wih_c = (const float*)d_in[10];
    const float* Whh_c = (const float*)d_in[11];
    const float* bih_c = (const float*)d_in[12];
    const float* bhh_c = (const float*)d_in[13];
    const float* Wout  = (const float*)d_in[14];
    const float* bout  = (const float*)d_in[15];
    const float* h0f   = (const float*)d_in[16];
    const float* c0f   = (const float*)d_in[17];
    const float* h0b   = (const float*)d_in[18];
    const float* c0b   = (const float*)d_in[19];
    const float* h0c   = (const float*)d_in[20];
    const float* c0c   = (const float*)d_in[21];

    // ws bump allocation (~44 MiB), all 16B-aligned
    char* p = (char*)d_ws;
    u16* Wfsw = (u16*)p; p += (size_t)2048 * 1024 * 2;          // 4 MB
    u16* Wbsw = (u16*)p; p += (size_t)2048 * 1024 * 2;          // 4 MB
    u16* Wcsw = (u16*)p; p += (size_t)4096 * 2048 * 2;          // 16 MB
    u16* Xfrag = (u16*)p; p += (size_t)8388608 * 2;             // 16 MB
    float* bsf = (float*)p; p += 2048 * 4;
    float* bsb = (float*)p; p += 2048 * 4;
    float* bsc = (float*)p; p += 4096 * 4;
    u16* hf[2]; hf[0] = (u16*)p; p += 131072 * 2; hf[1] = (u16*)p; p += 131072 * 2;
    u16* hb[2]; hb[0] = (u16*)p; p += 131072 * 2; hb[1] = (u16*)p; p += 131072 * 2;
    u16* hc[2]; hc[0] = (u16*)p; p += 262144 * 2; hc[1] = (u16*)p; p += 262144 * 2;
    float* cf = (float*)p; p += 131072 * 4;
    float* cb = (float*)p; p += 131072 * 4;
    float* cc = (float*)p; p += 262144 * 4;

    pack_k<<<dim3(2560), dim3(256), 0, stream>>>(
        x, W_emb, Wih_f, Whh_f, Wih_b, Whh_b, Wih_c, Whh_c,
        Xfrag, Wfsw, Wbsw, Wcsw);
    init_k<<<dim3(1024), dim3(256), 0, stream>>>(
        bih_f, bhh_f, bih_b, bhh_b, bih_c, bhh_c,
        h0f, c0f, h0b, c0b, h0c, c0c,
        bsf, bsb, bsc, hf[0], hb[0], hc[0], cf, cb, cc);

    // fb(s): reads h[s&1], writes h[(s+1)&1].  comb(s): reads hf/hb[(s+1)&1],
    // hc[s&1]; writes hc[(s+1)&1]. Launch t runs fb(t) + comb(t-1).
    for (int t = 0; t <= SS; ++t) {
        step_k<<<dim3(256), dim3(256), 0, stream>>>(
            Xfrag, Wfsw, Wbsw, Wcsw, bsf, bsb, bsc,
            hf[t & 1], hf[(t + 1) & 1], cf,
            hb[t & 1], hb[(t + 1) & 1], cb,
            hc[(t + 1) & 1], hc[t & 1], cc, t);
    }
    // final comb(63) wrote hc[0]
    head_v3<<<dim3(500), dim3(256), 0, stream>>>(hc[0], Wout, bout, (float*)d_out);
}